// Round 7
// baseline (260.300 us; speedup 1.0000x reference)
//
#include <hip/hip_runtime.h>
#include <stdint.h>
#include <math.h>

// Problem constants (fixed by setup_inputs)
#define B_ROWS 16384
#define D_DIM  1024
#define OUT_N  4096

typedef __bf16 bf16x8 __attribute__((ext_vector_type(8)));
typedef float  f32x4  __attribute__((ext_vector_type(4)));

__device__ __forceinline__ unsigned short f2bf(float f) {
  union { float f; uint32_t u; } v; v.f = f;
  uint32_t u = v.u;
  u += 0x7FFFu + ((u >> 16) & 1u);   // round-to-nearest-even
  return (unsigned short)(u >> 16);
}

// ---------------- prep kernel v2: one row per wave, no LDS/barriers ----------------
// rows [0, B_ROWS): x -> xbf + beta ; rows [B_ROWS, +OUT_N): z -> zbf + zp
__global__ void prep_kernel(const float* __restrict__ x,
                            const float* __restrict__ z,
                            const float* __restrict__ r,
                            const float* __restrict__ bias,
                            unsigned short* __restrict__ xbf,
                            unsigned short* __restrict__ zbf,
                            float* __restrict__ beta,
                            float4* __restrict__ zp) {
  const int wave = threadIdx.x >> 6;
  const int lane = threadIdx.x & 63;
  const int b = blockIdx.x * 4 + wave;        // global row id
  const bool isx = (b < B_ROWS);
  const int row = isx ? b : (b - B_ROWS);
  const float* src = (isx ? x : z) + (size_t)row * D_DIM;
  unsigned short* dst = (isx ? xbf : zbf) + (size_t)row * D_DIM;

  float ssq = 0.0f;
#pragma unroll
  for (int i = 0; i < 4; ++i) {
    const float4 v = reinterpret_cast<const float4*>(src)[i * 64 + lane];
    ssq += v.x * v.x + v.y * v.y + v.z * v.z + v.w * v.w;
    ushort4 h;
    h.x = f2bf(v.x); h.y = f2bf(v.y); h.z = f2bf(v.z); h.w = f2bf(v.w);
    reinterpret_cast<ushort4*>(dst)[i * 64 + lane] = h;
  }
#pragma unroll
  for (int off = 32; off > 0; off >>= 1) ssq += __shfl_down(ssq, off);
  if (lane == 0) {
    if (isx) {
      beta[row] = sqrtf(1.0f + ssq);   // sqrt(1 - K*x^2), K = -1
    } else {
      float zn = fmaxf(sqrtf(ssq), 1e-15f);
      float sr = fminf(fmaxf(r[row], -15.0f), 15.0f);
      float ch = coshf(sr), sh = sinhf(sr);
      const float LOG2E = 1.4426950408889634f;
      zp[row] = make_float4(ch / zn, sh, zn, bias[row] * LOG2E);
    }
  }
}

// ---------------- fused GEMM (256x256 8-phase, 16x16x32 MFMA) + epilogue ----------------

__device__ __forceinline__ void gload_lds16(const void* g, void* l) {
  __builtin_amdgcn_global_load_lds((__attribute__((address_space(1))) void*)g,
                                   (__attribute__((address_space(3))) void*)l,
                                   16, 0, 0);
}

#define FENCE() asm volatile("" ::: "memory")
#define BARRIER() do { FENCE(); __builtin_amdgcn_s_barrier(); FENCE(); } while (0)
#define WAITVM4() asm volatile("s_waitcnt vmcnt(4)" ::: "memory")
#define WAITVM0() asm volatile("s_waitcnt vmcnt(0)" ::: "memory")

// Stage one half-tile (128 rows x 64 cols bf16 = 16 KB) into LDS.
// Linear LDS dest; swizzle via pre-swizzled per-lane GLOBAL source (rule #21):
// logical 16B chunk q of row r lives at physical slot q ^ (r&7).
__device__ __forceinline__ void stage_half(const unsigned short* __restrict__ src,
                                           int grow0, int k0,
                                           unsigned short* ldsbase,
                                           int wave, int lane) {
#pragma unroll
  for (int j = 0; j < 2; ++j) {
    const int c = wave * 2 + j;                 // chunk 0..15, wave-uniform
    const int r = c * 8 + (lane >> 3);          // row within half
    const int col8 = (lane & 7) ^ (lane >> 3);  // inverse-swizzled source chunk
    gload_lds16(src + (size_t)(grow0 + r) * D_DIM + k0 + col8 * 8,
                ldsbase + c * 512);             // 1024 B per chunk
  }
}

__device__ __forceinline__ void load_a(bf16x8 a[4][2], const unsigned short* Ab,
                                       int qm, int lrow, int lgrp) {
  const int key = lrow & 7;
#pragma unroll
  for (int mi = 0; mi < 4; ++mi)
#pragma unroll
    for (int ks = 0; ks < 2; ++ks)
      a[mi][ks] = *reinterpret_cast<const bf16x8*>(
          &Ab[(qm * 64 + mi * 16 + lrow) * 64 + ((ks * 4 + lgrp) ^ key) * 8]);
}

__device__ __forceinline__ void load_b(bf16x8 b[2][2], const unsigned short* Bb,
                                       int qn, int lrow, int lgrp) {
  const int key = lrow & 7;
#pragma unroll
  for (int ni = 0; ni < 2; ++ni)
#pragma unroll
    for (int ks = 0; ks < 2; ++ks)
      b[ni][ks] = *reinterpret_cast<const bf16x8*>(
          &Bb[(qn * 32 + ni * 16 + lrow) * 64 + ((ks * 4 + lgrp) ^ key) * 8]);
}

__device__ __forceinline__ void mma_quad(f32x4 acc[8][4], const bf16x8 a[4][2],
                                         const bf16x8 b[2][2], int qm, int qn) {
  __builtin_amdgcn_s_setprio(1);
#pragma unroll
  for (int mi = 0; mi < 4; ++mi)
#pragma unroll
    for (int ni = 0; ni < 2; ++ni)
#pragma unroll
      for (int ks = 0; ks < 2; ++ks)
        acc[qm * 4 + mi][qn * 2 + ni] = __builtin_amdgcn_mfma_f32_16x16x32_bf16(
            a[mi][ks], b[ni][ks], acc[qm * 4 + mi][qn * 2 + ni], 0, 0, 0);
  __builtin_amdgcn_s_setprio(0);
}

// LDS layout (ushort offsets): buf b: b*32768 | A: +0, B: +16384 | half h: +8192
// within half: row r (0..127): r*64, 16B chunk c: c*8 (physical, swizzled)
__global__ __launch_bounds__(512) void gemm_fused(
    const unsigned short* __restrict__ xbf,
    const unsigned short* __restrict__ zbf,
    const float* __restrict__ beta,
    const float4* __restrict__ zp,
    float* __restrict__ out) {
  __shared__ unsigned short lds[65536];   // 128 KiB

  const int t = threadIdx.x;
  const int lane = t & 63;
  const int wave = t >> 6;
  const int wm = wave >> 2;      // 0..1
  const int wn = wave & 3;       // 0..3
  const int lrow = lane & 15;
  const int lgrp = lane >> 4;

  // XCD-aware mapping: XCD owns an 8-tile m-band (A 4 MB, L2-resident); m fast,
  // n slow (8 consecutive blocks share one B-tile). Bijective over 1024 blocks.
  const int bid = blockIdx.x;
  const int xcd = bid & 7;
  const int j   = bid >> 3;
  const int m0 = (xcd * 8 + (j & 7)) * 256;
  const int n0 = (j >> 3) * 256;

  unsigned short* A0 = lds + wm * 8192;                          // buf0.A (my half)
  unsigned short* A1 = lds + 32768 + wm * 8192;                  // buf1.A
  unsigned short* B0 = lds + 16384 + (wn >> 1) * 8192 + (wn & 1) * 4096;  // buf0.B (my 64 rows)
  unsigned short* B1 = B0 + 32768;                               // buf1.B

  f32x4 acc[8][4] = {};
  // persistent per-half fragment registers (96 VGPR): occupancy is LDS-limited
  // (1 block/CU at 128 KiB), so the register headroom is free.
  bf16x8 aL[4][2], aH[4][2], b0[2][2], b1[2][2];

  // ---- prologue: tile0 (buf0 full) + tile1 B (buf1.B); leave buf1.B in flight
  stage_half(xbf, m0,       0, lds,                 wave, lane);
  stage_half(xbf, m0 + 128, 0, lds + 8192,          wave, lane);
  stage_half(zbf, n0,       0, lds + 16384,         wave, lane);
  stage_half(zbf, n0 + 128, 0, lds + 16384 + 8192,  wave, lane);
  stage_half(zbf, n0,      64, lds + 32768 + 16384,        wave, lane);
  stage_half(zbf, n0 + 128,64, lds + 32768 + 16384 + 8192, wave, lane);
  WAITVM4();   // tile0 fully landed; tile1.B still in flight
  BARRIER();

#pragma unroll 1
  for (int i = 0; i < 8; ++i) {
    const int kA1 = (2 * i + 1) * 64;   // odd tile this iteration (buf1)
    const int kT2 = (2 * i + 2) * 64;   // next even tile (buf0)
    const int kT3 = (2 * i + 3) * 64;   // next odd tile (buf1)
    const bool more = (i < 7);

    // ---- P1: hoist ALL buf0 fragment reads (valid since prev WAITVM4+barrier);
    //      their completion hides under P1's MFMA; P2-P4 run from registers.
    load_a(aL, A0, 0, lrow, lgrp);
    load_a(aH, A0, 1, lrow, lgrp);
    load_b(b0, B0, 0, lrow, lgrp);
    load_b(b1, B0, 1, lrow, lgrp);
    stage_half(xbf, m0, kA1, lds + 32768, wave, lane);
    BARRIER();
    mma_quad(acc, aL, b0, 0, 0);
    BARRIER();
    // ---- P2: stage buf1.A.h1
    stage_half(xbf, m0 + 128, kA1, lds + 32768 + 8192, wave, lane);
    BARRIER();
    mma_quad(acc, aL, b1, 0, 1);
    BARRIER();
    // ---- P3: stage buf0.B.h0 (tile 2i+2)
    if (more) stage_half(zbf, n0, kT2, lds + 16384, wave, lane);
    BARRIER();
    mma_quad(acc, aH, b0, 1, 0);
    BARRIER();
    // ---- P4: stage buf0.B.h1; counted vmcnt
    if (more) stage_half(zbf, n0 + 128, kT2, lds + 16384 + 8192, wave, lane);
    BARRIER();
    mma_quad(acc, aH, b1, 1, 1);
    if (more) { WAITVM4(); } else { WAITVM0(); }
    BARRIER();

    // ---- P5: hoist ALL buf1 fragment reads (valid: A staged P1/P2, B staged
    //      prev P7/P8 -- all drained by P4's WAITVM4+barrier).
    load_a(aL, A1, 0, lrow, lgrp);
    load_a(aH, A1, 1, lrow, lgrp);
    load_b(b0, B1, 0, lrow, lgrp);
    load_b(b1, B1, 1, lrow, lgrp);
    if (more) stage_half(xbf, m0, kT2, lds, wave, lane);
    BARRIER();
    mma_quad(acc, aL, b0, 0, 0);
    BARRIER();
    // ---- P6: stage buf0.A.h1
    if (more) stage_half(xbf, m0 + 128, kT2, lds + 8192, wave, lane);
    BARRIER();
    mma_quad(acc, aL, b1, 0, 1);
    BARRIER();
    // ---- P7: stage buf1.B.h0 (tile 2i+3)
    if (more) stage_half(zbf, n0, kT3, lds + 32768 + 16384, wave, lane);
    BARRIER();
    mma_quad(acc, aH, b0, 1, 0);
    BARRIER();
    // ---- P8: stage buf1.B.h1; counted vmcnt
    if (more) stage_half(zbf, n0 + 128, kT3, lds + 32768 + 16384 + 8192, wave, lane);
    BARRIER();
    mma_quad(acc, aH, b1, 1, 1);
    if (more) WAITVM4();
    BARRIER();
  }

  // ---- epilogue: arg = (cosh/zn)*xz - sinh*beta;
  // y = sinh(zn*asinh(clip(arg)) + bias) = 0.5*(e - 1/e),
  // e = exp2( copysign(zn,arg)*log2(ax+sqrt(ax^2+1)) + bias*log2e )
  // ni-innermost store order: full 256B row segments -> no write amplification.
  float4 pq[4];
#pragma unroll
  for (int ni = 0; ni < 4; ++ni) pq[ni] = zp[n0 + wn * 64 + ni * 16 + lrow];
  const int ocol0 = n0 + wn * 64 + lrow;

#pragma unroll
  for (int mi = 0; mi < 8; ++mi) {
    const int r0 = m0 + wm * 128 + mi * 16 + lgrp * 4;
    const float4 b4 = *reinterpret_cast<const float4*>(&beta[r0]);
    const float btv[4] = {b4.x, b4.y, b4.z, b4.w};
#pragma unroll
    for (int jj = 0; jj < 4; ++jj) {
      const size_t rowbase = (size_t)(r0 + jj) * OUT_N + ocol0;
#pragma unroll
      for (int ni = 0; ni < 4; ++ni) {
        float acv = acc[mi][ni][jj];
        float arg = fmaf(pq[ni].x, acv, -(pq[ni].y * btv[jj]));
        float ax  = fminf(fabsf(arg), 1e6f);
        float s   = __builtin_amdgcn_sqrtf(fmaf(ax, ax, 1.0f));
        float tl  = __builtin_amdgcn_logf(ax + s);          // log2(ax + sqrt(ax^2+1))
        float zs  = copysignf(pq[ni].z, arg);
        float e   = __builtin_amdgcn_exp2f(fmaf(zs, tl, pq[ni].w));
        float rc  = __builtin_amdgcn_rcpf(e);
        out[rowbase + ni * 16] = fmaf(-0.5f, rc, 0.5f * e);
      }
    }
  }
}

// ---------------- launch ----------------

extern "C" void kernel_launch(void* const* d_in, const int* in_sizes, int n_in,
                              void* d_out, int out_size, void* d_ws, size_t ws_size,
                              hipStream_t stream) {
  const float* x    = (const float*)d_in[0];
  const float* z    = (const float*)d_in[1];
  const float* r    = (const float*)d_in[2];
  const float* bias = (const float*)d_in[3];
  float* out = (float*)d_out;

  char* ws = (char*)d_ws;
  unsigned short* xbf = (unsigned short*)ws;                               // 32 MB
  unsigned short* zbf = (unsigned short*)(ws + (size_t)32 * 1024 * 1024);  //  8 MB
  float* beta = (float*)(ws + (size_t)40 * 1024 * 1024);                   // 64 KB
  float4* zp  = (float4*)(ws + (size_t)40 * 1024 * 1024 + 64 * 1024);      // 64 KB

  prep_kernel<<<dim3((B_ROWS + OUT_N) / 4), dim3(256), 0, stream>>>(
      x, z, r, bias, xbf, zbf, beta, zp);
  gemm_fused<<<dim3((B_ROWS / 256) * (OUT_N / 256)), dim3(512), 0, stream>>>(
      xbf, zbf, beta, zp, out);
}

// Round 9
// 253.965 us; speedup vs baseline: 1.0249x; 1.0249x over previous
//
#include <hip/hip_runtime.h>
#include <stdint.h>
#include <math.h>

// Problem constants (fixed by setup_inputs)
#define B_ROWS 16384
#define D_DIM  1024
#define OUT_N  4096

typedef __bf16 bf16x8 __attribute__((ext_vector_type(8)));
typedef float  f32x4  __attribute__((ext_vector_type(4)));

__device__ __forceinline__ unsigned short f2bf(float f) {
  union { float f; uint32_t u; } v; v.f = f;
  uint32_t u = v.u;
  u += 0x7FFFu + ((u >> 16) & 1u);   // round-to-nearest-even
  return (unsigned short)(u >> 16);
}

// ---------------- prep kernel v2: one row per wave, no LDS/barriers ----------------
// rows [0, B_ROWS): x -> xbf + beta ; rows [B_ROWS, +OUT_N): z -> zbf + zp
__global__ void prep_kernel(const float* __restrict__ x,
                            const float* __restrict__ z,
                            const float* __restrict__ r,
                            const float* __restrict__ bias,
                            unsigned short* __restrict__ xbf,
                            unsigned short* __restrict__ zbf,
                            float* __restrict__ beta,
                            float4* __restrict__ zp) {
  const int wave = threadIdx.x >> 6;
  const int lane = threadIdx.x & 63;
  const int b = blockIdx.x * 4 + wave;        // global row id
  const bool isx = (b < B_ROWS);
  const int row = isx ? b : (b - B_ROWS);
  const float* src = (isx ? x : z) + (size_t)row * D_DIM;
  unsigned short* dst = (isx ? xbf : zbf) + (size_t)row * D_DIM;

  float ssq = 0.0f;
#pragma unroll
  for (int i = 0; i < 4; ++i) {
    const float4 v = reinterpret_cast<const float4*>(src)[i * 64 + lane];
    ssq += v.x * v.x + v.y * v.y + v.z * v.z + v.w * v.w;
    ushort4 h;
    h.x = f2bf(v.x); h.y = f2bf(v.y); h.z = f2bf(v.z); h.w = f2bf(v.w);
    reinterpret_cast<ushort4*>(dst)[i * 64 + lane] = h;
  }
#pragma unroll
  for (int off = 32; off > 0; off >>= 1) ssq += __shfl_down(ssq, off);
  if (lane == 0) {
    if (isx) {
      beta[row] = sqrtf(1.0f + ssq);   // sqrt(1 - K*x^2), K = -1
    } else {
      float zn = fmaxf(sqrtf(ssq), 1e-15f);
      float sr = fminf(fmaxf(r[row], -15.0f), 15.0f);
      float ch = coshf(sr), sh = sinhf(sr);
      const float LOG2E = 1.4426950408889634f;
      zp[row] = make_float4(ch / zn, sh, zn, bias[row] * LOG2E);
    }
  }
}

// ---------------- fused GEMM (256x256 8-phase, 16x16x32 MFMA) + epilogue ----------------

__device__ __forceinline__ void gload_lds16(const void* g, void* l) {
  __builtin_amdgcn_global_load_lds((__attribute__((address_space(1))) void*)g,
                                   (__attribute__((address_space(3))) void*)l,
                                   16, 0, 0);
}

#define FENCE() asm volatile("" ::: "memory")
#define BARRIER() do { FENCE(); __builtin_amdgcn_s_barrier(); FENCE(); } while (0)
#define WAITVM4() asm volatile("s_waitcnt vmcnt(4)" ::: "memory")
#define WAITVM0() asm volatile("s_waitcnt vmcnt(0)" ::: "memory")

// Stage one half-tile (128 rows x 64 cols bf16 = 16 KB) into LDS.
// Linear LDS dest; swizzle via pre-swizzled per-lane GLOBAL source (rule #21):
// logical 16B chunk q of row r lives at physical slot q ^ (r&7).
__device__ __forceinline__ void stage_half(const unsigned short* __restrict__ src,
                                           int grow0, int k0,
                                           unsigned short* ldsbase,
                                           int wave, int lane) {
#pragma unroll
  for (int j = 0; j < 2; ++j) {
    const int c = wave * 2 + j;                 // chunk 0..15, wave-uniform
    const int r = c * 8 + (lane >> 3);          // row within half
    const int col8 = (lane & 7) ^ (lane >> 3);  // inverse-swizzled source chunk
    gload_lds16(src + (size_t)(grow0 + r) * D_DIM + k0 + col8 * 8,
                ldsbase + c * 512);             // 1024 B per chunk
  }
}

__device__ __forceinline__ void load_a(bf16x8 a[4][2], const unsigned short* Ab,
                                       int qm, int lrow, int lgrp) {
  const int key = lrow & 7;
#pragma unroll
  for (int mi = 0; mi < 4; ++mi)
#pragma unroll
    for (int ks = 0; ks < 2; ++ks)
      a[mi][ks] = *reinterpret_cast<const bf16x8*>(
          &Ab[(qm * 64 + mi * 16 + lrow) * 64 + ((ks * 4 + lgrp) ^ key) * 8]);
}

__device__ __forceinline__ void load_b(bf16x8 b[2][2], const unsigned short* Bb,
                                       int qn, int lrow, int lgrp) {
  const int key = lrow & 7;
#pragma unroll
  for (int ni = 0; ni < 2; ++ni)
#pragma unroll
    for (int ks = 0; ks < 2; ++ks)
      b[ni][ks] = *reinterpret_cast<const bf16x8*>(
          &Bb[(qn * 32 + ni * 16 + lrow) * 64 + ((ks * 4 + lgrp) ^ key) * 8]);
}

__device__ __forceinline__ void mma_quad(f32x4 acc[8][4], const bf16x8 a[4][2],
                                         const bf16x8 b[2][2], int qm, int qn) {
  __builtin_amdgcn_s_setprio(1);
#pragma unroll
  for (int mi = 0; mi < 4; ++mi)
#pragma unroll
    for (int ni = 0; ni < 2; ++ni)
#pragma unroll
      for (int ks = 0; ks < 2; ++ks)
        acc[qm * 4 + mi][qn * 2 + ni] = __builtin_amdgcn_mfma_f32_16x16x32_bf16(
            a[mi][ks], b[ni][ks], acc[qm * 4 + mi][qn * 2 + ni], 0, 0, 0);
  __builtin_amdgcn_s_setprio(0);
}

// LDS layout (ushort offsets): buf b: b*32768 | A: +0, B: +16384 | half h: +8192
// within half: row r (0..127): r*64, 16B chunk c: c*8 (physical, swizzled)
//
// __launch_bounds__(512, 2): 2 waves/EU matches the LDS-forced occupancy
// (1 block/CU at 128 KiB) -> 256-VGPR budget. The R7 spill came from the
// default 128-reg budget; the K-loop peak here is acc 128 + frags 96 + ~15.
//
// RACE RULE (learned in R8): all fragment reads of a buffer must complete
// before any phase re-stages that buffer. All buf0 reads are in P1 (buf0.B
// restaged at P3/P4); all buf1 reads in P5 (buf1.B restaged at P7/P8).
__global__ __launch_bounds__(512, 2) void gemm_fused(
    const unsigned short* __restrict__ xbf,
    const unsigned short* __restrict__ zbf,
    const float* __restrict__ beta,
    const float4* __restrict__ zp,
    float* __restrict__ out) {
  __shared__ unsigned short lds[65536];   // 128 KiB

  const int t = threadIdx.x;
  const int lane = t & 63;
  const int wave = t >> 6;
  const int wm = wave >> 2;      // 0..1
  const int wn = wave & 3;       // 0..3
  const int lrow = lane & 15;
  const int lgrp = lane >> 4;

  // XCD-aware mapping: XCD owns an 8-tile m-band (A 4 MB, L2-resident); m fast,
  // n slow (8 consecutive blocks share one B-tile). Bijective over 1024 blocks.
  const int bid = blockIdx.x;
  const int xcd = bid & 7;
  const int j   = bid >> 3;
  const int m0 = (xcd * 8 + (j & 7)) * 256;
  const int n0 = (j >> 3) * 256;

  unsigned short* A0 = lds + wm * 8192;                          // buf0.A (my half)
  unsigned short* A1 = lds + 32768 + wm * 8192;                  // buf1.A
  unsigned short* B0 = lds + 16384 + (wn >> 1) * 8192 + (wn & 1) * 4096;  // buf0.B (my 64 rows)
  unsigned short* B1 = B0 + 32768;                               // buf1.B

  f32x4 acc[8][4] = {};
  // persistent per-half fragment registers (96 VGPR), hoisted to P1/P5.
  bf16x8 aL[4][2], aH[4][2], b0[2][2], b1[2][2];

  // ---- prologue: tile0 (buf0 full) + tile1 B (buf1.B); leave buf1.B in flight
  stage_half(xbf, m0,       0, lds,                 wave, lane);
  stage_half(xbf, m0 + 128, 0, lds + 8192,          wave, lane);
  stage_half(zbf, n0,       0, lds + 16384,         wave, lane);
  stage_half(zbf, n0 + 128, 0, lds + 16384 + 8192,  wave, lane);
  stage_half(zbf, n0,      64, lds + 32768 + 16384,        wave, lane);
  stage_half(zbf, n0 + 128,64, lds + 32768 + 16384 + 8192, wave, lane);
  WAITVM4();   // tile0 fully landed; tile1.B still in flight
  BARRIER();

#pragma unroll 1
  for (int i = 0; i < 8; ++i) {
    const int kA1 = (2 * i + 1) * 64;   // odd tile this iteration (buf1)
    const int kT2 = (2 * i + 2) * 64;   // next even tile (buf0)
    const int kT3 = (2 * i + 3) * 64;   // next odd tile (buf1)
    const bool more = (i < 7);

    // ---- P1: hoist ALL buf0 fragment reads (valid since prev WAITVM4+barrier;
    //      no buf0 restaging until P3). Completion hides under P1's MFMA;
    //      P2-P4 run pure-register. Stage buf1.A.h0.
    load_a(aL, A0, 0, lrow, lgrp);
    load_b(b0, B0, 0, lrow, lgrp);
    load_a(aH, A0, 1, lrow, lgrp);
    load_b(b1, B0, 1, lrow, lgrp);
    stage_half(xbf, m0, kA1, lds + 32768, wave, lane);
    BARRIER();
    mma_quad(acc, aL, b0, 0, 0);
    BARRIER();
    // ---- P2: stage buf1.A.h1
    stage_half(xbf, m0 + 128, kA1, lds + 32768 + 8192, wave, lane);
    BARRIER();
    mma_quad(acc, aL, b1, 0, 1);
    BARRIER();
    // ---- P3: stage buf0.B.h0 (tile 2i+2)
    if (more) stage_half(zbf, n0, kT2, lds + 16384, wave, lane);
    BARRIER();
    mma_quad(acc, aH, b0, 1, 0);
    BARRIER();
    // ---- P4: stage buf0.B.h1; counted vmcnt
    if (more) stage_half(zbf, n0 + 128, kT2, lds + 16384 + 8192, wave, lane);
    BARRIER();
    mma_quad(acc, aH, b1, 1, 1);
    if (more) { WAITVM4(); } else { WAITVM0(); }
    BARRIER();

    // ---- P5: hoist ALL buf1 fragment reads (A staged P1/P2, B staged prev
    //      P7/P8 -- all drained by P4's WAITVM4+barrier; no buf1 restaging
    //      until P7). Stage buf0.A.h0 (tile 2i+2).
    load_a(aL, A1, 0, lrow, lgrp);
    load_b(b0, B1, 0, lrow, lgrp);
    load_a(aH, A1, 1, lrow, lgrp);
    load_b(b1, B1, 1, lrow, lgrp);
    if (more) stage_half(xbf, m0, kT2, lds, wave, lane);
    BARRIER();
    mma_quad(acc, aL, b0, 0, 0);
    BARRIER();
    // ---- P6: stage buf0.A.h1
    if (more) stage_half(xbf, m0 + 128, kT2, lds + 8192, wave, lane);
    BARRIER();
    mma_quad(acc, aL, b1, 0, 1);
    BARRIER();
    // ---- P7: stage buf1.B.h0 (tile 2i+3)
    if (more) stage_half(zbf, n0, kT3, lds + 32768 + 16384, wave, lane);
    BARRIER();
    mma_quad(acc, aH, b0, 1, 0);
    BARRIER();
    // ---- P8: stage buf1.B.h1; counted vmcnt
    if (more) stage_half(zbf, n0 + 128, kT3, lds + 32768 + 16384 + 8192, wave, lane);
    BARRIER();
    mma_quad(acc, aH, b1, 1, 1);
    if (more) WAITVM4();
    BARRIER();
  }

  // ---- epilogue: arg = (cosh/zn)*xz - sinh*beta;
  // y = sinh(zn*asinh(clip(arg)) + bias) = 0.5*(e - 1/e),
  // e = exp2( copysign(zn,arg)*log2(ax+sqrt(ax^2+1)) + bias*log2e )
  // ni-innermost store order: full 256B row segments -> no write amplification.
  float4 pq[4];
#pragma unroll
  for (int ni = 0; ni < 4; ++ni) pq[ni] = zp[n0 + wn * 64 + ni * 16 + lrow];
  const int ocol0 = n0 + wn * 64 + lrow;

#pragma unroll
  for (int mi = 0; mi < 8; ++mi) {
    const int r0 = m0 + wm * 128 + mi * 16 + lgrp * 4;
    const float4 b4 = *reinterpret_cast<const float4*>(&beta[r0]);
    const float btv[4] = {b4.x, b4.y, b4.z, b4.w};
#pragma unroll
    for (int jj = 0; jj < 4; ++jj) {
      const size_t rowbase = (size_t)(r0 + jj) * OUT_N + ocol0;
#pragma unroll
      for (int ni = 0; ni < 4; ++ni) {
        float acv = acc[mi][ni][jj];
        float arg = fmaf(pq[ni].x, acv, -(pq[ni].y * btv[jj]));
        float ax  = fminf(fabsf(arg), 1e6f);
        float s   = __builtin_amdgcn_sqrtf(fmaf(ax, ax, 1.0f));
        float tl  = __builtin_amdgcn_logf(ax + s);          // log2(ax + sqrt(ax^2+1))
        float zs  = copysignf(pq[ni].z, arg);
        float e   = __builtin_amdgcn_exp2f(fmaf(zs, tl, pq[ni].w));
        float rc  = __builtin_amdgcn_rcpf(e);
        out[rowbase + ni * 16] = fmaf(-0.5f, rc, 0.5f * e);
      }
    }
  }
}

// ---------------- launch ----------------

extern "C" void kernel_launch(void* const* d_in, const int* in_sizes, int n_in,
                              void* d_out, int out_size, void* d_ws, size_t ws_size,
                              hipStream_t stream) {
  const float* x    = (const float*)d_in[0];
  const float* z    = (const float*)d_in[1];
  const float* r    = (const float*)d_in[2];
  const float* bias = (const float*)d_in[3];
  float* out = (float*)d_out;

  char* ws = (char*)d_ws;
  unsigned short* xbf = (unsigned short*)ws;                               // 32 MB
  unsigned short* zbf = (unsigned short*)(ws + (size_t)32 * 1024 * 1024);  //  8 MB
  float* beta = (float*)(ws + (size_t)40 * 1024 * 1024);                   // 64 KB
  float4* zp  = (float4*)(ws + (size_t)40 * 1024 * 1024 + 64 * 1024);      // 64 KB

  prep_kernel<<<dim3((B_ROWS + OUT_N) / 4), dim3(256), 0, stream>>>(
      x, z, r, bias, xbf, zbf, beta, zp);
  gemm_fused<<<dim3((B_ROWS / 256) * (OUT_N / 256)), dim3(512), 0, stream>>>(
      xbf, zbf, beta, zp, out);
}

// Round 10
// 196.081 us; speedup vs baseline: 1.3275x; 1.2952x over previous
//
#include <hip/hip_runtime.h>
#include <stdint.h>
#include <math.h>

// Problem constants (fixed by setup_inputs)
#define B_ROWS 16384
#define D_DIM  1024
#define OUT_N  4096

typedef __bf16 bf16x8 __attribute__((ext_vector_type(8)));
typedef float  f32x4  __attribute__((ext_vector_type(4)));

__device__ __forceinline__ unsigned short f2bf(float f) {
  union { float f; uint32_t u; } v; v.f = f;
  uint32_t u = v.u;
  u += 0x7FFFu + ((u >> 16) & 1u);   // round-to-nearest-even
  return (unsigned short)(u >> 16);
}

// ---------------- prep kernel v2: one row per wave, no LDS/barriers ----------------
// rows [0, B_ROWS): x -> xbf + beta ; rows [B_ROWS, +OUT_N): z -> zbf + zp
__global__ void prep_kernel(const float* __restrict__ x,
                            const float* __restrict__ z,
                            const float* __restrict__ r,
                            const float* __restrict__ bias,
                            unsigned short* __restrict__ xbf,
                            unsigned short* __restrict__ zbf,
                            float* __restrict__ beta,
                            float4* __restrict__ zp) {
  const int wave = threadIdx.x >> 6;
  const int lane = threadIdx.x & 63;
  const int b = blockIdx.x * 4 + wave;        // global row id
  const bool isx = (b < B_ROWS);
  const int row = isx ? b : (b - B_ROWS);
  const float* src = (isx ? x : z) + (size_t)row * D_DIM;
  unsigned short* dst = (isx ? xbf : zbf) + (size_t)row * D_DIM;

  float ssq = 0.0f;
#pragma unroll
  for (int i = 0; i < 4; ++i) {
    const float4 v = reinterpret_cast<const float4*>(src)[i * 64 + lane];
    ssq += v.x * v.x + v.y * v.y + v.z * v.z + v.w * v.w;
    ushort4 h;
    h.x = f2bf(v.x); h.y = f2bf(v.y); h.z = f2bf(v.z); h.w = f2bf(v.w);
    reinterpret_cast<ushort4*>(dst)[i * 64 + lane] = h;
  }
#pragma unroll
  for (int off = 32; off > 0; off >>= 1) ssq += __shfl_down(ssq, off);
  if (lane == 0) {
    if (isx) {
      beta[row] = sqrtf(1.0f + ssq);   // sqrt(1 - K*x^2), K = -1
    } else {
      float zn = fmaxf(sqrtf(ssq), 1e-15f);
      float sr = fminf(fmaxf(r[row], -15.0f), 15.0f);
      float ch = coshf(sr), sh = sinhf(sr);
      const float LOG2E = 1.4426950408889634f;
      zp[row] = make_float4(ch / zn, sh, zn, bias[row] * LOG2E);
    }
  }
}

// ---------------- fused GEMM (256x256, 4 merged phases/iter, 16x16x32) ----------------

__device__ __forceinline__ void gload_lds16(const void* g, void* l) {
  __builtin_amdgcn_global_load_lds((__attribute__((address_space(1))) void*)g,
                                   (__attribute__((address_space(3))) void*)l,
                                   16, 0, 0);
}

#define FENCE() asm volatile("" ::: "memory")
#define BARRIER() do { FENCE(); __builtin_amdgcn_s_barrier(); FENCE(); } while (0)
#define WAITVM4() asm volatile("s_waitcnt vmcnt(4)" ::: "memory")
#define WAITVM0() asm volatile("s_waitcnt vmcnt(0)" ::: "memory")

// Stage one half-tile (128 rows x 64 cols bf16 = 16 KB) into LDS.
// Linear LDS dest; swizzle via pre-swizzled per-lane GLOBAL source (rule #21):
// logical 16B chunk q of row r lives at physical slot q ^ (r&7).
__device__ __forceinline__ void stage_half(const unsigned short* __restrict__ src,
                                           int grow0, int k0,
                                           unsigned short* ldsbase,
                                           int wave, int lane) {
#pragma unroll
  for (int j = 0; j < 2; ++j) {
    const int c = wave * 2 + j;                 // chunk 0..15, wave-uniform
    const int r = c * 8 + (lane >> 3);          // row within half
    const int col8 = (lane & 7) ^ (lane >> 3);  // inverse-swizzled source chunk
    gload_lds16(src + (size_t)(grow0 + r) * D_DIM + k0 + col8 * 8,
                ldsbase + c * 512);             // 1024 B per chunk
  }
}

__device__ __forceinline__ void load_a(bf16x8 a[4][2], const unsigned short* Ab,
                                       int qm, int lrow, int lgrp) {
  const int key = lrow & 7;
#pragma unroll
  for (int mi = 0; mi < 4; ++mi)
#pragma unroll
    for (int ks = 0; ks < 2; ++ks)
      a[mi][ks] = *reinterpret_cast<const bf16x8*>(
          &Ab[(qm * 64 + mi * 16 + lrow) * 64 + ((ks * 4 + lgrp) ^ key) * 8]);
}

__device__ __forceinline__ void load_b(bf16x8 b[2][2], const unsigned short* Bb,
                                       int qn, int lrow, int lgrp) {
  const int key = lrow & 7;
#pragma unroll
  for (int ni = 0; ni < 2; ++ni)
#pragma unroll
    for (int ks = 0; ks < 2; ++ks)
      b[ni][ks] = *reinterpret_cast<const bf16x8*>(
          &Bb[(qn * 32 + ni * 16 + lrow) * 64 + ((ks * 4 + lgrp) ^ key) * 8]);
}

// one half-row of the wave tile: quads (qm,0) and (qm,1) = 32 MFMA in one
// setprio cluster. b1 is consumed only in the second quad, so its ds_read
// (issued last) hides under the first quad's MFMAs via fine-grained lgkmcnt.
__device__ __forceinline__ void mma_half(f32x4 acc[8][4], const bf16x8 a[4][2],
                                         const bf16x8 b0[2][2], const bf16x8 b1[2][2],
                                         int qm) {
  __builtin_amdgcn_s_setprio(1);
#pragma unroll
  for (int mi = 0; mi < 4; ++mi)
#pragma unroll
    for (int ni = 0; ni < 2; ++ni)
#pragma unroll
      for (int ks = 0; ks < 2; ++ks)
        acc[qm * 4 + mi][ni] = __builtin_amdgcn_mfma_f32_16x16x32_bf16(
            a[mi][ks], b0[ni][ks], acc[qm * 4 + mi][ni], 0, 0, 0);
#pragma unroll
  for (int mi = 0; mi < 4; ++mi)
#pragma unroll
    for (int ni = 0; ni < 2; ++ni)
#pragma unroll
      for (int ks = 0; ks < 2; ++ks)
        acc[qm * 4 + mi][2 + ni] = __builtin_amdgcn_mfma_f32_16x16x32_bf16(
            a[mi][ks], b1[ni][ks], acc[qm * 4 + mi][2 + ni], 0, 0, 0);
  __builtin_amdgcn_s_setprio(0);
}

// LDS layout (ushort offsets): buf b: b*32768 | A: +0, B: +16384 | half h: +8192
// within half: row r (0..127): r*64, 16B chunk c: c*8 (physical, swizzled)
//
// 4 merged phases per iteration (2 K-tiles): 32 MFMA + 2 half-stages each,
// 8 barriers/iter (was 16). Peak live fragments = 64 VGPR (aL|aH + b0 + b1),
// same as the proven R6 kernel -> no spill at the 128-VGPR + 128-AGPR budget
// (the unified file is FULL at 2 waves/SIMD; persistent-frag hoists spill).
//
// RACE RULE: each fragment is read AND consumed within one phase, before the
// barrier that precedes its buffer region's re-staging; no phase both reads
// and re-stages the same region.
__global__ __launch_bounds__(512) void gemm_fused(
    const unsigned short* __restrict__ xbf,
    const unsigned short* __restrict__ zbf,
    const float* __restrict__ beta,
    const float4* __restrict__ zp,
    float* __restrict__ out) {
  __shared__ unsigned short lds[65536];   // 128 KiB

  const int t = threadIdx.x;
  const int lane = t & 63;
  const int wave = t >> 6;
  const int wm = wave >> 2;      // 0..1
  const int wn = wave & 3;       // 0..3
  const int lrow = lane & 15;
  const int lgrp = lane >> 4;

  // XCD-aware mapping: XCD owns an 8-tile m-band (A 4 MB, L2-resident); m fast,
  // n slow (8 consecutive blocks share one B-tile). Bijective over 1024 blocks.
  const int bid = blockIdx.x;
  const int xcd = bid & 7;
  const int j   = bid >> 3;
  const int m0 = (xcd * 8 + (j & 7)) * 256;
  const int n0 = (j >> 3) * 256;

  unsigned short* A0 = lds + wm * 8192;                          // buf0.A (my half)
  unsigned short* A1 = lds + 32768 + wm * 8192;                  // buf1.A
  unsigned short* B0 = lds + 16384 + (wn >> 1) * 8192 + (wn & 1) * 4096;  // buf0.B (my 64 rows)
  unsigned short* B1 = B0 + 32768;                               // buf1.B

  f32x4 acc[8][4] = {};
  bf16x8 aL[4][2], aH[4][2], b0[2][2], b1[2][2];

  // ---- prologue: buf0 full (tile0) + buf1.B (tile1); leave buf1.B in flight
  stage_half(xbf, m0,       0, lds,                 wave, lane);
  stage_half(xbf, m0 + 128, 0, lds + 8192,          wave, lane);
  stage_half(zbf, n0,       0, lds + 16384,         wave, lane);
  stage_half(zbf, n0 + 128, 0, lds + 16384 + 8192,  wave, lane);
  stage_half(zbf, n0,      64, lds + 32768 + 16384,        wave, lane);
  stage_half(zbf, n0 + 128,64, lds + 32768 + 16384 + 8192, wave, lane);
  WAITVM4();   // tile0 fully landed; tile1.B (4 loads) still in flight
  BARRIER();

#pragma unroll 1
  for (int i = 0; i < 8; ++i) {
    const int kA1 = (2 * i + 1) * 64;   // odd tile this iteration (buf1)
    const int kT2 = (2 * i + 2) * 64;   // next even tile (buf0)
    const int kT3 = (2 * i + 3) * 64;   // next odd tile (buf1)
    const bool more = (i < 7);

    // ---- P1: read aL,b0,b1 <- buf0; stage buf1.A h0+h1 (tile 2i+1)
    load_a(aL, A0, 0, lrow, lgrp);
    load_b(b0, B0, 0, lrow, lgrp);
    load_b(b1, B0, 1, lrow, lgrp);
    stage_half(xbf, m0,       kA1, lds + 32768,        wave, lane);
    stage_half(xbf, m0 + 128, kA1, lds + 32768 + 8192, wave, lane);
    BARRIER();
    mma_half(acc, aL, b0, b1, 0);
    BARRIER();

    // ---- P2: read aH <- buf0.A; stage buf0.B h0+h1 (tile 2i+2); counted vmcnt
    load_a(aH, A0, 1, lrow, lgrp);
    if (more) {
      stage_half(zbf, n0,       kT2, lds + 16384,        wave, lane);
      stage_half(zbf, n0 + 128, kT2, lds + 16384 + 8192, wave, lane);
    }
    BARRIER();
    mma_half(acc, aH, b0, b1, 1);
    // drain prevP4.buf1.B + P1.buf1.A (oldest 8 of 12) -> buf1 ready for P3
    if (more) { WAITVM4(); } else { WAITVM0(); }
    BARRIER();

    // ---- P3: read aL,b0,b1 <- buf1; stage buf0.A h0+h1 (tile 2i+2)
    load_a(aL, A1, 0, lrow, lgrp);
    load_b(b0, B1, 0, lrow, lgrp);
    load_b(b1, B1, 1, lrow, lgrp);
    if (more) {
      stage_half(xbf, m0,       kT2, lds,        wave, lane);
      stage_half(xbf, m0 + 128, kT2, lds + 8192, wave, lane);
    }
    BARRIER();
    mma_half(acc, aL, b0, b1, 0);
    BARRIER();

    // ---- P4: read aH <- buf1.A; stage buf1.B h0+h1 (tile 2i+3); counted vmcnt
    load_a(aH, A1, 1, lrow, lgrp);
    if (more) {
      stage_half(zbf, n0,       kT3, lds + 32768 + 16384,        wave, lane);
      stage_half(zbf, n0 + 128, kT3, lds + 32768 + 16384 + 8192, wave, lane);
    }
    BARRIER();
    mma_half(acc, aH, b0, b1, 1);
    // drain P2.buf0.B + P3.buf0.A (oldest 8 of 12) -> buf0 ready for next P1
    if (more) WAITVM4();
    BARRIER();
  }

  // ---- epilogue: arg = (cosh/zn)*xz - sinh*beta;
  // y = sinh(zn*asinh(clip(arg)) + bias) = 0.5*(e - 1/e),
  // e = exp2( copysign(zn,arg)*log2(ax+sqrt(ax^2+1)) + bias*log2e )
  // ni-innermost store order: full 256B row segments -> no write amplification.
  float4 pq[4];
#pragma unroll
  for (int ni = 0; ni < 4; ++ni) pq[ni] = zp[n0 + wn * 64 + ni * 16 + lrow];
  const int ocol0 = n0 + wn * 64 + lrow;

#pragma unroll
  for (int mi = 0; mi < 8; ++mi) {
    const int r0 = m0 + wm * 128 + mi * 16 + lgrp * 4;
    const float4 b4 = *reinterpret_cast<const float4*>(&beta[r0]);
    const float btv[4] = {b4.x, b4.y, b4.z, b4.w};
#pragma unroll
    for (int jj = 0; jj < 4; ++jj) {
      const size_t rowbase = (size_t)(r0 + jj) * OUT_N + ocol0;
#pragma unroll
      for (int ni = 0; ni < 4; ++ni) {
        float acv = acc[mi][ni][jj];
        float arg = fmaf(pq[ni].x, acv, -(pq[ni].y * btv[jj]));
        float ax  = fminf(fabsf(arg), 1e6f);
        float s   = __builtin_amdgcn_sqrtf(fmaf(ax, ax, 1.0f));
        float tl  = __builtin_amdgcn_logf(ax + s);          // log2(ax + sqrt(ax^2+1))
        float zs  = copysignf(pq[ni].z, arg);
        float e   = __builtin_amdgcn_exp2f(fmaf(zs, tl, pq[ni].w));
        float rc  = __builtin_amdgcn_rcpf(e);
        out[rowbase + ni * 16] = fmaf(-0.5f, rc, 0.5f * e);
      }
    }
  }
}

// ---------------- launch ----------------

extern "C" void kernel_launch(void* const* d_in, const int* in_sizes, int n_in,
                              void* d_out, int out_size, void* d_ws, size_t ws_size,
                              hipStream_t stream) {
  const float* x    = (const float*)d_in[0];
  const float* z    = (const float*)d_in[1];
  const float* r    = (const float*)d_in[2];
  const float* bias = (const float*)d_in[3];
  float* out = (float*)d_out;

  char* ws = (char*)d_ws;
  unsigned short* xbf = (unsigned short*)ws;                               // 32 MB
  unsigned short* zbf = (unsigned short*)(ws + (size_t)32 * 1024 * 1024);  //  8 MB
  float* beta = (float*)(ws + (size_t)40 * 1024 * 1024);                   // 64 KB
  float4* zp  = (float4*)(ws + (size_t)40 * 1024 * 1024 + 64 * 1024);      // 64 KB

  prep_kernel<<<dim3((B_ROWS + OUT_N) / 4), dim3(256), 0, stream>>>(
      x, z, r, bias, xbf, zbf, beta, zp);
  gemm_fused<<<dim3((B_ROWS / 256) * (OUT_N / 256)), dim3(512), 0, stream>>>(
      xbf, zbf, beta, zp, out);
}